// Round 13
// baseline (61.670 us; speedup 1.0000x reference)
//
#include <hip/hip_runtime.h>
#include <hip/hip_bf16.h>

typedef __attribute__((ext_vector_type(8))) short s8v;     // 8 bf16 = 16B
typedef __attribute__((ext_vector_type(4))) float f4v;     // fp32 accum

__device__ __forceinline__ ushort f2bf(float f) {
    __hip_bfloat16 h = __float2bfloat16(f);
    return __builtin_bit_cast(ushort, h);
}

__device__ __forceinline__ int fsw(int row) { return ((row >> 1) ^ (row >> 3)) & 3; }

__device__ __forceinline__ void cvtw16(ushort* p, float4 a, float4 b) {
    s8v u;
    u[0] = (short)f2bf(a.x); u[1] = (short)f2bf(a.y);
    u[2] = (short)f2bf(a.z); u[3] = (short)f2bf(a.w);
    u[4] = (short)f2bf(b.x); u[5] = (short)f2bf(b.y);
    u[6] = (short)f2bf(b.z); u[7] = (short)f2bf(b.w);
    *(s8v*)p = u;
}

__device__ __forceinline__ void scatw(ushort* L, int c8, int d, float4 a, float4 b) {
    float v[8] = { a.x, a.y, a.z, a.w, b.x, b.y, b.z, b.w };
#pragma unroll
    for (int i = 0; i < 8; ++i) {
        int row = c8 + i;
        L[row * 32 + (((d >> 3) ^ fsw(row)) << 3) + (d & 7)] = f2bf(v[i]);
    }
}

__device__ __forceinline__ s8v ld8(const ushort* p) { return *(const s8v*)p; }

// ===== 64x64 S-GEMM from fp32 (S = x @ x^T, ld 1024), 8 waves split-K.
__device__ __forceinline__ void gemmS(
    const float* __restrict__ Xb, ushort* lds, int row0, int col0,
    ushort* __restrict__ S, int mirror) {
    const int NT = 16;
    const int tid = threadIdx.x, wave = tid >> 6, lane = tid & 63;
    const int g = wave >> 2, w4 = wave & 3;
    const int wr = w4 >> 1, wc = w4 & 1;
    const int rA = lane & 15, kg = lane >> 4;
    const int tg = tid & 255;
    const int srow = tg >> 2, slot = tg & 3;
    const int kb = g * (NT * 32);
    ushort* LA = lds + g * 16384;
    ushort* LB = LA + 8192;
    const int wadr = srow * 32 + ((slot ^ fsw(srow)) << 3);
    const float* gx = Xb + (size_t)(row0 + srow) * 1024 + kb + slot * 8;
    const float* gy = Xb + (size_t)(col0 + srow) * 1024 + kb + slot * 8;
    f4v acc[2][2] = {};
    __syncthreads();

    float4 bx[4][2], by[4][2];
#pragma unroll
    for (int p = 0; p < 3; ++p) {
        bx[p][0] = *(const float4*)(gx + p * 32);
        bx[p][1] = *(const float4*)(gx + p * 32 + 4);
        by[p][0] = *(const float4*)(gy + p * 32);
        by[p][1] = *(const float4*)(gy + p * 32 + 4);
    }
    cvtw16(LA + wadr, bx[0][0], bx[0][1]);
    cvtw16(LB + wadr, by[0][0], by[0][1]);

#pragma unroll
    for (int t = 0; t < NT; ++t) {
        if (t + 3 < NT) {
            const int bi = (t + 3) & 3;
            bx[bi][0] = *(const float4*)(gx + (t + 3) * 32);
            bx[bi][1] = *(const float4*)(gx + (t + 3) * 32 + 4);
            by[bi][0] = *(const float4*)(gy + (t + 3) * 32);
            by[bi][1] = *(const float4*)(gy + (t + 3) * 32 + 4);
        }
        if (t + 1 < NT) {
            const int bi = (t + 1) & 3;
            cvtw16(LA + ((t + 1) & 3) * 2048 + wadr, bx[bi][0], bx[bi][1]);
            cvtw16(LB + ((t + 1) & 3) * 2048 + wadr, by[bi][0], by[bi][1]);
        }
        asm volatile("s_waitcnt lgkmcnt(0)" ::: "memory");
        __builtin_amdgcn_s_barrier();
        __builtin_amdgcn_sched_barrier(0);
        const ushort* pa = LA + (t & 3) * 2048;
        const ushort* pb = LB + (t & 3) * 2048;
        s8v a[2], b[2];
#pragma unroll
        for (int m = 0; m < 2; ++m) {
            int row = wr * 32 + m * 16 + rA;
            a[m] = *(const s8v*)&pa[row * 32 + ((kg ^ fsw(row)) << 3)];
        }
#pragma unroll
        for (int n = 0; n < 2; ++n) {
            int row = wc * 32 + n * 16 + rA;
            b[n] = *(const s8v*)&pb[row * 32 + ((kg ^ fsw(row)) << 3)];
        }
#pragma unroll
        for (int m = 0; m < 2; ++m)
#pragma unroll
            for (int n = 0; n < 2; ++n)
                acc[m][n] = __builtin_amdgcn_mfma_f32_16x16x32_bf16(a[m], b[n], acc[m][n], 0, 0, 0);
    }
    __syncthreads();
    float* red = (float*)lds;
    if (g == 1) {
#pragma unroll
        for (int m = 0; m < 2; ++m)
#pragma unroll
            for (int n = 0; n < 2; ++n)
                *(f4v*)&red[(w4 * 64 + lane) * 16 + (m * 2 + n) * 4] = acc[m][n];
    }
    __syncthreads();
    if (g == 0) {
        int r4 = (lane >> 4) * 4, cl = lane & 15;
#pragma unroll
        for (int m = 0; m < 2; ++m)
#pragma unroll
            for (int n = 0; n < 2; ++n) {
                f4v o = *(const f4v*)&red[(w4 * 64 + lane) * 16 + (m * 2 + n) * 4];
                f4v s = acc[m][n] + o;
                int row = row0 + wr * 32 + m * 16 + r4;
                int col = col0 + wc * 32 + n * 16 + cl;
                ushort4 tv = { f2bf(s[0]), f2bf(s[1]), f2bf(s[2]), f2bf(s[3]) };
                S[(size_t)(row + 0) * 256 + col] = tv.x;
                S[(size_t)(row + 1) * 256 + col] = tv.y;
                S[(size_t)(row + 2) * 256 + col] = tv.z;
                S[(size_t)(row + 3) * 256 + col] = tv.w;
                if (mirror)
                    *(ushort4*)&S[(size_t)col * 256 + row] = tv;
            }
    }
}

// ===== 64x64 weight-GEMM from fp32 (K=256, split-K). XT=1: X transposed =====
template<int XT>
__device__ __forceinline__ void gemmWT(
    const float* __restrict__ Xw, const float* __restrict__ Yw,
    ushort* lds, int row0, int col0, ushort* __restrict__ O, int ldo) {
    const int NT = 4;
    const int tid = threadIdx.x, wave = tid >> 6, lane = tid & 63;
    const int g = wave >> 2, w4 = wave & 3;
    const int wr = w4 >> 1, wc = w4 & 1;
    const int rA = lane & 15, kg = lane >> 4;
    const int tg = tid & 255;
    const int kb = g * 128;
    ushort* LA = lds + g * 16384;
    ushort* LB = LA + 8192;
    const int dT = tg >> 3, c8 = (tg & 7) * 8;
    const int srow = tg >> 2, slot = tg & 3;
    const int wadr = srow * 32 + ((slot ^ fsw(srow)) << 3);
    f4v acc[2][2] = {};
    __syncthreads();

    float4 bx[4][2], by[4][2];
#pragma unroll
    for (int p = 0; p < 3; ++p) {
        if (XT) {
            bx[p][0] = *(const float4*)(Xw + (size_t)(kb + p * 32 + dT) * 256 + row0 + c8);
            bx[p][1] = *(const float4*)(Xw + (size_t)(kb + p * 32 + dT) * 256 + row0 + c8 + 4);
        } else {
            bx[p][0] = *(const float4*)(Xw + (size_t)(row0 + srow) * 1024 + kb + p * 32 + slot * 8);
            bx[p][1] = *(const float4*)(Xw + (size_t)(row0 + srow) * 1024 + kb + p * 32 + slot * 8 + 4);
        }
        by[p][0] = *(const float4*)(Yw + (size_t)(kb + p * 32 + dT) * 256 + col0 + c8);
        by[p][1] = *(const float4*)(Yw + (size_t)(kb + p * 32 + dT) * 256 + col0 + c8 + 4);
    }
    if (XT) scatw(LA, c8, dT, bx[0][0], bx[0][1]);
    else    cvtw16(LA + wadr, bx[0][0], bx[0][1]);
    scatw(LB, c8, dT, by[0][0], by[0][1]);

#pragma unroll
    for (int t = 0; t < NT; ++t) {
        if (t + 3 < NT) {
            const int bi = (t + 3) & 3;
            if (XT) {
                bx[bi][0] = *(const float4*)(Xw + (size_t)(kb + (t + 3) * 32 + dT) * 256 + row0 + c8);
                bx[bi][1] = *(const float4*)(Xw + (size_t)(kb + (t + 3) * 32 + dT) * 256 + row0 + c8 + 4);
            } else {
                bx[bi][0] = *(const float4*)(Xw + (size_t)(row0 + srow) * 1024 + kb + (t + 3) * 32 + slot * 8);
                bx[bi][1] = *(const float4*)(Xw + (size_t)(row0 + srow) * 1024 + kb + (t + 3) * 32 + slot * 8 + 4);
            }
            by[bi][0] = *(const float4*)(Yw + (size_t)(kb + (t + 3) * 32 + dT) * 256 + col0 + c8);
            by[bi][1] = *(const float4*)(Yw + (size_t)(kb + (t + 3) * 32 + dT) * 256 + col0 + c8 + 4);
        }
        if (t + 1 < NT) {
            const int bi = (t + 1) & 3;
            ushort* la = LA + ((t + 1) & 3) * 2048;
            ushort* lb = LB + ((t + 1) & 3) * 2048;
            if (XT) scatw(la, c8, dT, bx[bi][0], bx[bi][1]);
            else    cvtw16(la + wadr, bx[bi][0], bx[bi][1]);
            scatw(lb, c8, dT, by[bi][0], by[bi][1]);
        }
        asm volatile("s_waitcnt lgkmcnt(0)" ::: "memory");
        __builtin_amdgcn_s_barrier();
        __builtin_amdgcn_sched_barrier(0);
        const ushort* pa = LA + (t & 3) * 2048;
        const ushort* pb = LB + (t & 3) * 2048;
        s8v a[2], b[2];
#pragma unroll
        for (int m = 0; m < 2; ++m) {
            int row = wr * 32 + m * 16 + rA;
            a[m] = *(const s8v*)&pa[row * 32 + ((kg ^ fsw(row)) << 3)];
        }
#pragma unroll
        for (int n = 0; n < 2; ++n) {
            int row = wc * 32 + n * 16 + rA;
            b[n] = *(const s8v*)&pb[row * 32 + ((kg ^ fsw(row)) << 3)];
        }
#pragma unroll
        for (int m = 0; m < 2; ++m)
#pragma unroll
            for (int n = 0; n < 2; ++n)
                acc[m][n] = __builtin_amdgcn_mfma_f32_16x16x32_bf16(a[m], b[n], acc[m][n], 0, 0, 0);
    }
    __syncthreads();
    float* red = (float*)lds;
    if (g == 1) {
#pragma unroll
        for (int m = 0; m < 2; ++m)
#pragma unroll
            for (int n = 0; n < 2; ++n)
                *(f4v*)&red[(w4 * 64 + lane) * 16 + (m * 2 + n) * 4] = acc[m][n];
    }
    __syncthreads();
    if (g == 0) {
        int r4 = (lane >> 4) * 4, cl = lane & 15;
#pragma unroll
        for (int m = 0; m < 2; ++m)
#pragma unroll
            for (int n = 0; n < 2; ++n) {
                f4v o = *(const f4v*)&red[(w4 * 64 + lane) * 16 + (m * 2 + n) * 4];
                f4v s = acc[m][n] + o;
                int row = row0 + wr * 32 + m * 16 + r4;
                int col = col0 + wc * 32 + n * 16 + cl;
#pragma unroll
                for (int r = 0; r < 4; ++r)
                    O[(size_t)(row + r) * ldo + col] = f2bf(s[r]);
            }
    }
}

// ===== direct-fragment 64x64 wave GEMM: no LDS, no barriers. K = NT*32.
//       Fragments loaded straight global->VGPR (K-contig rows), 3-slot pipeline.
template<int NT, int OBF>
__device__ __forceinline__ void gemmDF64(
    const ushort* __restrict__ X, const ushort* __restrict__ Y,
    int ldx, int ldy, int row0, int col0,
    void* __restrict__ Oraw, int ldo, const float* __restrict__ bias) {
    const int lane = threadIdx.x & 63;
    const int rA = lane & 15, kg = lane >> 4;
    const ushort* ax = X + (size_t)(row0 + rA) * ldx + kg * 8;
    const ushort* by = Y + (size_t)(col0 + rA) * ldy + kg * 8;
    f4v acc[4][4] = {};
    s8v a[3][4], b[3][4];
#pragma unroll
    for (int p = 0; p < 2; ++p) {
#pragma unroll
        for (int m = 0; m < 4; ++m) a[p][m] = ld8(ax + (size_t)m * 16 * ldx + p * 32);
#pragma unroll
        for (int n = 0; n < 4; ++n) b[p][n] = ld8(by + (size_t)n * 16 * ldy + p * 32);
    }
#pragma unroll
    for (int t = 0; t < NT; ++t) {
        if (t + 2 < NT) {
            const int s = (t + 2) % 3;
#pragma unroll
            for (int m = 0; m < 4; ++m) a[s][m] = ld8(ax + (size_t)m * 16 * ldx + (t + 2) * 32);
#pragma unroll
            for (int n = 0; n < 4; ++n) b[s][n] = ld8(by + (size_t)n * 16 * ldy + (t + 2) * 32);
        }
        const int c = t % 3;
#pragma unroll
        for (int m = 0; m < 4; ++m)
#pragma unroll
            for (int n = 0; n < 4; ++n)
                acc[m][n] = __builtin_amdgcn_mfma_f32_16x16x32_bf16(a[c][m], b[c][n], acc[m][n], 0, 0, 0);
    }
    const int r4 = (lane >> 4) * 4, cl = lane & 15;
    if (OBF) {
        ushort* O = (ushort*)Oraw;
#pragma unroll
        for (int m = 0; m < 4; ++m)
#pragma unroll
            for (int n = 0; n < 4; ++n) {
                int row = row0 + m * 16 + r4;
                int col = col0 + n * 16 + cl;
#pragma unroll
                for (int r = 0; r < 4; ++r)
                    O[(size_t)(row + r) * ldo + col] = f2bf(acc[m][n][r]);
            }
    } else {
        float* O = (float*)Oraw;
#pragma unroll
        for (int m = 0; m < 4; ++m)
#pragma unroll
            for (int n = 0; n < 4; ++n) {
                int row = row0 + m * 16 + r4;
                int col = col0 + n * 16 + cl;
#pragma unroll
                for (int r = 0; r < 4; ++r)
                    O[(size_t)(row + r) * ldo + col] = acc[m][n][r] + bias[row + r];
            }
    }
}

// ===== direct-fragment 32x32 wave GEMM (K = NT*32), 4-slot pipeline =====
template<int NT>
__device__ __forceinline__ void gemmDF32(
    const ushort* __restrict__ X, const ushort* __restrict__ Y,
    int ldx, int ldy, int row0, int col0, ushort* __restrict__ O, int ldo) {
    const int lane = threadIdx.x & 63;
    const int rA = lane & 15, kg = lane >> 4;
    const ushort* ax = X + (size_t)(row0 + rA) * ldx + kg * 8;
    const ushort* by = Y + (size_t)(col0 + rA) * ldy + kg * 8;
    f4v acc[2][2] = {};
    s8v a[4][2], b[4][2];
#pragma unroll
    for (int p = 0; p < 3; ++p) {
#pragma unroll
        for (int m = 0; m < 2; ++m) a[p][m] = ld8(ax + (size_t)m * 16 * ldx + p * 32);
#pragma unroll
        for (int n = 0; n < 2; ++n) b[p][n] = ld8(by + (size_t)n * 16 * ldy + p * 32);
    }
#pragma unroll
    for (int t = 0; t < NT; ++t) {
        if (t + 3 < NT) {
            const int s = (t + 3) & 3;
#pragma unroll
            for (int m = 0; m < 2; ++m) a[s][m] = ld8(ax + (size_t)m * 16 * ldx + (t + 3) * 32);
#pragma unroll
            for (int n = 0; n < 2; ++n) b[s][n] = ld8(by + (size_t)n * 16 * ldy + (t + 3) * 32);
        }
        const int c = t & 3;
#pragma unroll
        for (int m = 0; m < 2; ++m)
#pragma unroll
            for (int n = 0; n < 2; ++n)
                acc[m][n] = __builtin_amdgcn_mfma_f32_16x16x32_bf16(a[c][m], b[c][n], acc[m][n], 0, 0, 0);
    }
    const int r4 = (lane >> 4) * 4, cl = lane & 15;
#pragma unroll
    for (int m = 0; m < 2; ++m)
#pragma unroll
        for (int n = 0; n < 2; ++n) {
            int row = row0 + m * 16 + r4;
            int col = col0 + n * 16 + cl;
#pragma unroll
            for (int r = 0; r < 4; ++r)
                O[(size_t)(row + r) * ldo + col] = f2bf(acc[m][n][r]);
        }
}

// ===== kernel 1: 544 blocks x 512 thr.
//   0..159  : S upper-triangular tiles (10/batch, mirrored), XCD-mapped
//   160..223: A = Wq^T @ Wk   (64 tiles)
//   224..287: BT = Wo @ Wv^T  (64 tiles)
//   288..543: x -> xlc transpose (4 jobs each)
__global__ __launch_bounds__(512, 2) void kSP(
    const float* __restrict__ x, const float* __restrict__ Wq,
    const float* __restrict__ Wk, const float* __restrict__ Wv,
    const float* __restrict__ Wo,
    ushort* __restrict__ S16, ushort* __restrict__ A16,
    ushort* __restrict__ BT, ushort* __restrict__ xlc) {
    __shared__ __align__(16) ushort lds[32768];
    const int bid = blockIdx.x, tid = threadIdx.x;
    if (bid < 160) {
        int xcd = bid & 7, idx = bid >> 3;
        int b = 2 * xcd + (idx >= 10);
        int tri = (idx >= 10) ? idx - 10 : idx;
        int ti, tj;
        if (tri < 4)      { ti = 0; tj = tri; }
        else if (tri < 7) { ti = 1; tj = tri - 3; }
        else if (tri < 9) { ti = 2; tj = tri - 5; }
        else              { ti = 3; tj = 3; }
        const float* xb = x + (size_t)b * 262144;
        gemmS(xb, lds, ti * 64, tj * 64, S16 + (size_t)b * 65536, ti != tj);
    } else if (bid < 224) {
        int q = bid - 160, h = q >> 4, t2 = q & 15;
        gemmWT<1>(Wq + (size_t)h * 65536, Wk + (size_t)h * 65536, lds,
                  (t2 >> 2) * 64, (t2 & 3) * 64, A16 + (size_t)h * 65536, 256);
    } else if (bid < 288) {
        int q = bid - 224, h = q >> 4, t2 = q & 15;
        gemmWT<0>(Wo + (size_t)h * 256, Wv + (size_t)h * 65536, lds,
                  (t2 >> 2) * 64, (t2 & 3) * 64, BT + (size_t)h * 256, 1024);
    } else {
        ushort (*t)[72] = (ushort(*)[72])lds;
        int r = tid >> 3, c0 = (tid & 7) * 8;
#pragma unroll
        for (int rr = 0; rr < 4; ++rr) {
            int jid = (bid - 288) + 256 * rr;       // 0..1023
            __syncthreads();
            int lt = jid & 15, ct = (jid >> 4) & 3, b2 = jid >> 6;
            size_t so = (size_t)(b2 * 256 + ct * 64 + r) * 1024 + lt * 64 + c0;
            float4 v0 = *(const float4*)(x + so);
            float4 v1 = *(const float4*)(x + so + 4);
            ushort4 u0 = { f2bf(v0.x), f2bf(v0.y), f2bf(v0.z), f2bf(v0.w) };
            ushort4 u1 = { f2bf(v1.x), f2bf(v1.y), f2bf(v1.z), f2bf(v1.w) };
            *(ushort4*)&t[r][c0] = u0;
            *(ushort4*)&t[r][c0 + 4] = u1;
            __syncthreads();
            size_t dof = (size_t)(b2 * 1024 + lt * 64 + r) * 256 + ct * 64 + c0;
            ushort4 w0 = { t[c0][r], t[c0 + 1][r], t[c0 + 2][r], t[c0 + 3][r] };
            ushort4 w1 = { t[c0 + 4][r], t[c0 + 5][r], t[c0 + 6][r], t[c0 + 7][r] };
            *(ushort4*)(xlc + dof) = w0;
            *(ushort4*)(xlc + dof + 4) = w1;
        }
    }
}

// ===== kernel 2: T1_b[:, h*256:] = A_h @ S_b^T — 256 blocks x 4 waves, 64x64/wave
__global__ __launch_bounds__(256, 2) void kT1(
    const ushort* __restrict__ A16, const ushort* __restrict__ S16,
    ushort* __restrict__ T1) {
    int bid = blockIdx.x, wave = threadIdx.x >> 6;
    int xcd = bid & 7, idx = bid >> 3;            // 0..31
    int b = 2 * xcd + (idx >> 4);
    int tile = (idx & 15) * 4 + wave;             // 0..63
    int h = tile >> 4, r = (tile >> 2) & 3, c = tile & 3;
    gemmDF64<8, 1>(A16 + (size_t)h * 65536, S16 + (size_t)b * 65536, 256, 256,
                   r * 64, c * 64, T1 + (size_t)b * 262144 + h * 256, 1024, nullptr);
}

// ===== kernel 3: GT_b = BT @ T1_b^T (K=1024) — 256 blocks x 4 waves, 32x32/wave
__global__ __launch_bounds__(256, 2) void kGT(
    const ushort* __restrict__ BT, const ushort* __restrict__ T1,
    ushort* __restrict__ GT) {
    int bid = blockIdx.x, wave = threadIdx.x >> 6;
    int xcd = bid & 7, idx = bid >> 3;
    int b = 2 * xcd + (idx >> 4);
    int tile = (idx & 15) * 4 + wave;             // 0..63
    int rt = tile >> 3, ct = tile & 7;
    gemmDF32<32>(BT, T1 + (size_t)b * 262144, 1024, 1024,
                 rt * 32, ct * 32, GT + (size_t)b * 65536, 256);
}

// ===== kernel 4: out_b = GT_b @ xlc_b^T + bias — 256 blocks x 4 waves, 64x64/wave
__global__ __launch_bounds__(256, 2) void kOUT(
    const ushort* __restrict__ GT, const ushort* __restrict__ xlc,
    float* __restrict__ out, const float* __restrict__ bias) {
    int bid = blockIdx.x, wave = threadIdx.x >> 6;
    int xcd = bid & 7, idx = bid >> 3;
    int b = 2 * xcd + (idx >> 4);
    int tile = (idx & 15) * 4 + wave;             // 0..63
    int rt = tile >> 4, ct = tile & 15;
    gemmDF64<8, 0>(GT + (size_t)b * 65536, xlc + (size_t)b * 262144, 256, 256,
                   rt * 64, ct * 64, out + (size_t)b * 262144, 1024, bias);
}

extern "C" void kernel_launch(void* const* d_in, const int* in_sizes, int n_in,
                              void* d_out, int out_size, void* d_ws, size_t ws_size,
                              hipStream_t stream) {
    const float* x  = (const float*)d_in[0];
    const float* Wq = (const float*)d_in[1];
    const float* Wk = (const float*)d_in[2];
    const float* Wv = (const float*)d_in[3];
    const float* Wo = (const float*)d_in[4];
    const float* Wb = (const float*)d_in[5];

    char* ws = (char*)d_ws;
    ushort* T1  = (ushort*)(ws + 0);           // [16][256][1024] bf16, 8 MB
    ushort* xlc = (ushort*)(ws + 8388608);     // [16][1024][256] bf16, 8 MB
    ushort* S16 = (ushort*)(ws + 16777216);    // [16][256][256]  bf16, 2 MB
    ushort* GT  = (ushort*)(ws + 20971520);    // [16][256][256]  bf16, 2 MB
    ushort* A16 = (ushort*)(ws + 25165824);    // [4][256][256]   bf16, 512 KB
    ushort* BT  = (ushort*)(ws + 26214400);    // [256][1024]     bf16, 512 KB

    hipLaunchKernelGGL(kSP,  dim3(544), dim3(512), 0, stream,
                       x, Wq, Wk, Wv, Wo, S16, A16, BT, xlc);
    hipLaunchKernelGGL(kT1,  dim3(256), dim3(256), 0, stream, A16, S16, T1);
    hipLaunchKernelGGL(kGT,  dim3(256), dim3(256), 0, stream, BT, T1, GT);
    hipLaunchKernelGGL(kOUT, dim3(256), dim3(256), 0, stream, GT, xlc, (float*)d_out, Wb);
}

// Round 14
// 39.256 us; speedup vs baseline: 1.5710x; 1.5710x over previous
//
#include <hip/hip_runtime.h>
#include <hip/hip_bf16.h>

typedef __attribute__((ext_vector_type(8))) short s8v;     // 8 bf16 = 16B
typedef __attribute__((ext_vector_type(4))) float f4v;     // fp32 accum

__device__ __forceinline__ ushort f2bf(float f) {
    __hip_bfloat16 h = __float2bfloat16(f);
    return __builtin_bit_cast(ushort, h);
}

__device__ __forceinline__ int fsw(int row) { return ((row >> 1) ^ (row >> 3)) & 3; }

__device__ __forceinline__ void gload16(const ushort* g, ushort* l) {
    __builtin_amdgcn_global_load_lds(
        (const __attribute__((address_space(1))) unsigned*)g,
        (__attribute__((address_space(3))) unsigned*)l, 16, 0, 0);
}

__device__ __forceinline__ void cvtw16(ushort* p, float4 a, float4 b) {
    s8v u;
    u[0] = (short)f2bf(a.x); u[1] = (short)f2bf(a.y);
    u[2] = (short)f2bf(a.z); u[3] = (short)f2bf(a.w);
    u[4] = (short)f2bf(b.x); u[5] = (short)f2bf(b.y);
    u[6] = (short)f2bf(b.z); u[7] = (short)f2bf(b.w);
    *(s8v*)p = u;
}

__device__ __forceinline__ void scatw(ushort* L, int c8, int d, float4 a, float4 b) {
    float v[8] = { a.x, a.y, a.z, a.w, b.x, b.y, b.z, b.w };
#pragma unroll
    for (int i = 0; i < 8; ++i) {
        int row = c8 + i;
        L[row * 32 + (((d >> 3) ^ fsw(row)) << 3) + (d & 7)] = f2bf(v[i]);
    }
}

// ===== 64x64 S-GEMM from fp32 (S = x @ x^T, ld 1024), 8 waves split-K.
__device__ __forceinline__ void gemmS(
    const float* __restrict__ Xb, ushort* lds, int row0, int col0,
    ushort* __restrict__ S, int mirror) {
    const int NT = 16;
    const int tid = threadIdx.x, wave = tid >> 6, lane = tid & 63;
    const int g = wave >> 2, w4 = wave & 3;
    const int wr = w4 >> 1, wc = w4 & 1;
    const int rA = lane & 15, kg = lane >> 4;
    const int tg = tid & 255;
    const int srow = tg >> 2, slot = tg & 3;
    const int kb = g * (NT * 32);
    ushort* LA = lds + g * 16384;
    ushort* LB = LA + 8192;
    const int wadr = srow * 32 + ((slot ^ fsw(srow)) << 3);
    const float* gx = Xb + (size_t)(row0 + srow) * 1024 + kb + slot * 8;
    const float* gy = Xb + (size_t)(col0 + srow) * 1024 + kb + slot * 8;
    f4v acc[2][2] = {};
    __syncthreads();

    float4 bx[4][2], by[4][2];
#pragma unroll
    for (int p = 0; p < 3; ++p) {
        bx[p][0] = *(const float4*)(gx + p * 32);
        bx[p][1] = *(const float4*)(gx + p * 32 + 4);
        by[p][0] = *(const float4*)(gy + p * 32);
        by[p][1] = *(const float4*)(gy + p * 32 + 4);
    }
    cvtw16(LA + wadr, bx[0][0], bx[0][1]);
    cvtw16(LB + wadr, by[0][0], by[0][1]);

#pragma unroll
    for (int t = 0; t < NT; ++t) {
        if (t + 3 < NT) {
            const int bi = (t + 3) & 3;
            bx[bi][0] = *(const float4*)(gx + (t + 3) * 32);
            bx[bi][1] = *(const float4*)(gx + (t + 3) * 32 + 4);
            by[bi][0] = *(const float4*)(gy + (t + 3) * 32);
            by[bi][1] = *(const float4*)(gy + (t + 3) * 32 + 4);
        }
        if (t + 1 < NT) {
            const int bi = (t + 1) & 3;
            cvtw16(LA + ((t + 1) & 3) * 2048 + wadr, bx[bi][0], bx[bi][1]);
            cvtw16(LB + ((t + 1) & 3) * 2048 + wadr, by[bi][0], by[bi][1]);
        }
        asm volatile("s_waitcnt lgkmcnt(0)" ::: "memory");
        __builtin_amdgcn_s_barrier();
        __builtin_amdgcn_sched_barrier(0);
        const ushort* pa = LA + (t & 3) * 2048;
        const ushort* pb = LB + (t & 3) * 2048;
        s8v a[2], b[2];
#pragma unroll
        for (int m = 0; m < 2; ++m) {
            int row = wr * 32 + m * 16 + rA;
            a[m] = *(const s8v*)&pa[row * 32 + ((kg ^ fsw(row)) << 3)];
        }
#pragma unroll
        for (int n = 0; n < 2; ++n) {
            int row = wc * 32 + n * 16 + rA;
            b[n] = *(const s8v*)&pb[row * 32 + ((kg ^ fsw(row)) << 3)];
        }
#pragma unroll
        for (int m = 0; m < 2; ++m)
#pragma unroll
            for (int n = 0; n < 2; ++n)
                acc[m][n] = __builtin_amdgcn_mfma_f32_16x16x32_bf16(a[m], b[n], acc[m][n], 0, 0, 0);
    }
    __syncthreads();
    float* red = (float*)lds;
    if (g == 1) {
#pragma unroll
        for (int m = 0; m < 2; ++m)
#pragma unroll
            for (int n = 0; n < 2; ++n)
                *(f4v*)&red[(w4 * 64 + lane) * 16 + (m * 2 + n) * 4] = acc[m][n];
    }
    __syncthreads();
    if (g == 0) {
        int r4 = (lane >> 4) * 4, cl = lane & 15;
#pragma unroll
        for (int m = 0; m < 2; ++m)
#pragma unroll
            for (int n = 0; n < 2; ++n) {
                f4v o = *(const f4v*)&red[(w4 * 64 + lane) * 16 + (m * 2 + n) * 4];
                f4v s = acc[m][n] + o;
                int row = row0 + wr * 32 + m * 16 + r4;
                int col = col0 + wc * 32 + n * 16 + cl;
                ushort4 tv = { f2bf(s[0]), f2bf(s[1]), f2bf(s[2]), f2bf(s[3]) };
                S[(size_t)(row + 0) * 256 + col] = tv.x;
                S[(size_t)(row + 1) * 256 + col] = tv.y;
                S[(size_t)(row + 2) * 256 + col] = tv.z;
                S[(size_t)(row + 3) * 256 + col] = tv.w;
                if (mirror)
                    *(ushort4*)&S[(size_t)col * 256 + row] = tv;
            }
    }
}

// ===== 64x64 weight-GEMM from fp32 (K=256, split-K). XT=1: X transposed =====
template<int XT>
__device__ __forceinline__ void gemmWT(
    const float* __restrict__ Xw, const float* __restrict__ Yw,
    ushort* lds, int row0, int col0, ushort* __restrict__ O, int ldo) {
    const int NT = 4;
    const int tid = threadIdx.x, wave = tid >> 6, lane = tid & 63;
    const int g = wave >> 2, w4 = wave & 3;
    const int wr = w4 >> 1, wc = w4 & 1;
    const int rA = lane & 15, kg = lane >> 4;
    const int tg = tid & 255;
    const int kb = g * 128;
    ushort* LA = lds + g * 16384;
    ushort* LB = LA + 8192;
    const int dT = tg >> 3, c8 = (tg & 7) * 8;
    const int srow = tg >> 2, slot = tg & 3;
    const int wadr = srow * 32 + ((slot ^ fsw(srow)) << 3);
    f4v acc[2][2] = {};
    __syncthreads();

    float4 bx[4][2], by[4][2];
#pragma unroll
    for (int p = 0; p < 3; ++p) {
        if (XT) {
            bx[p][0] = *(const float4*)(Xw + (size_t)(kb + p * 32 + dT) * 256 + row0 + c8);
            bx[p][1] = *(const float4*)(Xw + (size_t)(kb + p * 32 + dT) * 256 + row0 + c8 + 4);
        } else {
            bx[p][0] = *(const float4*)(Xw + (size_t)(row0 + srow) * 1024 + kb + p * 32 + slot * 8);
            bx[p][1] = *(const float4*)(Xw + (size_t)(row0 + srow) * 1024 + kb + p * 32 + slot * 8 + 4);
        }
        by[p][0] = *(const float4*)(Yw + (size_t)(kb + p * 32 + dT) * 256 + col0 + c8);
        by[p][1] = *(const float4*)(Yw + (size_t)(kb + p * 32 + dT) * 256 + col0 + c8 + 4);
    }
    if (XT) scatw(LA, c8, dT, bx[0][0], bx[0][1]);
    else    cvtw16(LA + wadr, bx[0][0], bx[0][1]);
    scatw(LB, c8, dT, by[0][0], by[0][1]);

#pragma unroll
    for (int t = 0; t < NT; ++t) {
        if (t + 3 < NT) {
            const int bi = (t + 3) & 3;
            if (XT) {
                bx[bi][0] = *(const float4*)(Xw + (size_t)(kb + (t + 3) * 32 + dT) * 256 + row0 + c8);
                bx[bi][1] = *(const float4*)(Xw + (size_t)(kb + (t + 3) * 32 + dT) * 256 + row0 + c8 + 4);
            } else {
                bx[bi][0] = *(const float4*)(Xw + (size_t)(row0 + srow) * 1024 + kb + (t + 3) * 32 + slot * 8);
                bx[bi][1] = *(const float4*)(Xw + (size_t)(row0 + srow) * 1024 + kb + (t + 3) * 32 + slot * 8 + 4);
            }
            by[bi][0] = *(const float4*)(Yw + (size_t)(kb + (t + 3) * 32 + dT) * 256 + col0 + c8);
            by[bi][1] = *(const float4*)(Yw + (size_t)(kb + (t + 3) * 32 + dT) * 256 + col0 + c8 + 4);
        }
        if (t + 1 < NT) {
            const int bi = (t + 1) & 3;
            ushort* la = LA + ((t + 1) & 3) * 2048;
            ushort* lb = LB + ((t + 1) & 3) * 2048;
            if (XT) scatw(la, c8, dT, bx[bi][0], bx[bi][1]);
            else    cvtw16(la + wadr, bx[bi][0], bx[bi][1]);
            scatw(lb, c8, dT, by[bi][0], by[bi][1]);
        }
        asm volatile("s_waitcnt lgkmcnt(0)" ::: "memory");
        __builtin_amdgcn_s_barrier();
        __builtin_amdgcn_sched_barrier(0);
        const ushort* pa = LA + (t & 3) * 2048;
        const ushort* pb = LB + (t & 3) * 2048;
        s8v a[2], b[2];
#pragma unroll
        for (int m = 0; m < 2; ++m) {
            int row = wr * 32 + m * 16 + rA;
            a[m] = *(const s8v*)&pa[row * 32 + ((kg ^ fsw(row)) << 3)];
        }
#pragma unroll
        for (int n = 0; n < 2; ++n) {
            int row = wc * 32 + n * 16 + rA;
            b[n] = *(const s8v*)&pb[row * 32 + ((kg ^ fsw(row)) << 3)];
        }
#pragma unroll
        for (int m = 0; m < 2; ++m)
#pragma unroll
            for (int n = 0; n < 2; ++n)
                acc[m][n] = __builtin_amdgcn_mfma_f32_16x16x32_bf16(a[m], b[n], acc[m][n], 0, 0, 0);
    }
    __syncthreads();
    float* red = (float*)lds;
    if (g == 1) {
#pragma unroll
        for (int m = 0; m < 2; ++m)
#pragma unroll
            for (int n = 0; n < 2; ++n)
                *(f4v*)&red[(w4 * 64 + lane) * 16 + (m * 2 + n) * 4] = acc[m][n];
    }
    __syncthreads();
    if (g == 0) {
        int r4 = (lane >> 4) * 4, cl = lane & 15;
#pragma unroll
        for (int m = 0; m < 2; ++m)
#pragma unroll
            for (int n = 0; n < 2; ++n) {
                f4v o = *(const f4v*)&red[(w4 * 64 + lane) * 16 + (m * 2 + n) * 4];
                f4v s = acc[m][n] + o;
                int row = row0 + wr * 32 + m * 16 + r4;
                int col = col0 + wc * 32 + n * 16 + cl;
#pragma unroll
                for (int r = 0; r < 4; ++r)
                    O[(size_t)(row + r) * ldo + col] = f2bf(s[r]);
            }
    }
}

// ===== 64x64 bf16 GEMM (gload_lds), 8-wave split-K — GT stage (K=1024) =====
__device__ __forceinline__ void gemm64x8(
    const ushort* __restrict__ Xb, const ushort* __restrict__ Yb,
    int ldx, int ldy, ushort* lds, int row0, int col0, int K,
    ushort* __restrict__ O, int ldo) {
    const int tid = threadIdx.x, wave = tid >> 6, lane = tid & 63;
    const int g = wave >> 2, w4 = wave & 3;
    const int wr = w4 >> 1, wc = w4 & 1;
    const int rA = lane & 15, kg = lane >> 4;
    const int srow = w4 * 16 + (lane >> 2);
    const int scol = ((lane & 3) ^ fsw(srow)) * 8;
    const int K2 = K >> 1, NT = K2 >> 5, kb = g * K2;
    ushort* LA = lds + g * 16384;
    ushort* LB = LA + 8192;
    f4v acc[2][2] = {};
    __syncthreads();
    const ushort* gx = Xb + (size_t)(row0 + srow) * ldx + kb + scol;
    const ushort* gy = Yb + (size_t)(col0 + srow) * ldy + kb + scol;
    gload16(gx,      LA + w4 * 512);
    gload16(gy,      LB + w4 * 512);
    gload16(gx + 32, LA + 2048 + w4 * 512);
    gload16(gy + 32, LB + 2048 + w4 * 512);
    for (int t = 0; t < NT; ++t) {
        if (t + 2 < NT) {
            int s2 = (t + 2) & 3, kt = (t + 2) << 5;
            gload16(gx + kt, LA + s2 * 2048 + w4 * 512);
            gload16(gy + kt, LB + s2 * 2048 + w4 * 512);
            asm volatile("s_waitcnt vmcnt(4)" ::: "memory");
        } else if (t + 1 < NT) {
            asm volatile("s_waitcnt vmcnt(2)" ::: "memory");
        } else {
            asm volatile("s_waitcnt vmcnt(0)" ::: "memory");
        }
        __builtin_amdgcn_s_barrier();
        __builtin_amdgcn_sched_barrier(0);
        const ushort* pa = LA + (t & 3) * 2048;
        const ushort* pb = LB + (t & 3) * 2048;
        s8v a[2], b[2];
#pragma unroll
        for (int m = 0; m < 2; ++m) {
            int row = wr * 32 + m * 16 + rA;
            a[m] = *(const s8v*)&pa[row * 32 + ((kg ^ fsw(row)) << 3)];
        }
#pragma unroll
        for (int n = 0; n < 2; ++n) {
            int row = wc * 32 + n * 16 + rA;
            b[n] = *(const s8v*)&pb[row * 32 + ((kg ^ fsw(row)) << 3)];
        }
#pragma unroll
        for (int m = 0; m < 2; ++m)
#pragma unroll
            for (int n = 0; n < 2; ++n)
                acc[m][n] = __builtin_amdgcn_mfma_f32_16x16x32_bf16(a[m], b[n], acc[m][n], 0, 0, 0);
    }
    __syncthreads();
    float* red = (float*)lds;
    if (g == 1) {
#pragma unroll
        for (int m = 0; m < 2; ++m)
#pragma unroll
            for (int n = 0; n < 2; ++n)
                *(f4v*)&red[(w4 * 64 + lane) * 16 + (m * 2 + n) * 4] = acc[m][n];
    }
    __syncthreads();
    if (g == 0) {
        int r4 = (lane >> 4) * 4, cl = lane & 15;
#pragma unroll
        for (int m = 0; m < 2; ++m)
#pragma unroll
            for (int n = 0; n < 2; ++n) {
                f4v o = *(const f4v*)&red[(w4 * 64 + lane) * 16 + (m * 2 + n) * 4];
                f4v s = acc[m][n] + o;
                int row = row0 + wr * 32 + m * 16 + r4;
                int col = col0 + wc * 32 + n * 16 + cl;
#pragma unroll
                for (int r = 0; r < 4; ++r)
                    O[(size_t)(row + r) * ldo + col] = f2bf(s[r]);
            }
    }
}

// ===== 64x64 bf16 GEMM, 4 waves / 256 thr (gload_lds, 4-slot, counted vmcnt).
//       OBF=1: bf16 out; OBF=0: fp32 out + bias[row].  K = NT*32.
template<int NT, int OBF>
__device__ __forceinline__ void gemm64q(
    const ushort* __restrict__ X, const ushort* __restrict__ Y,
    int ldx, int ldy, ushort* lds, int row0, int col0,
    void* __restrict__ Oraw, int ldo, const float* __restrict__ bias) {
    const int tid = threadIdx.x, wave = tid >> 6, lane = tid & 63;
    const int wr = wave >> 1, wc = wave & 1;
    const int rA = lane & 15, kg = lane >> 4;
    const int srow = wave * 16 + (lane >> 2);
    const int scol = ((lane & 3) ^ fsw(srow)) * 8;
    ushort* LA = lds;            // 4 slots x 2048 ushorts
    ushort* LB = lds + 8192;
    f4v acc[2][2] = {};
    const ushort* gx = X + (size_t)(row0 + srow) * ldx + scol;
    const ushort* gy = Y + (size_t)(col0 + srow) * ldy + scol;
    gload16(gx,      LA + wave * 512);
    gload16(gy,      LB + wave * 512);
    gload16(gx + 32, LA + 2048 + wave * 512);
    gload16(gy + 32, LB + 2048 + wave * 512);
#pragma unroll
    for (int t = 0; t < NT; ++t) {
        if (t + 2 < NT) {
            int s2 = (t + 2) & 3, kt = (t + 2) << 5;
            gload16(gx + kt, LA + s2 * 2048 + wave * 512);
            gload16(gy + kt, LB + s2 * 2048 + wave * 512);
            asm volatile("s_waitcnt vmcnt(4)" ::: "memory");
        } else if (t + 1 < NT) {
            asm volatile("s_waitcnt vmcnt(2)" ::: "memory");
        } else {
            asm volatile("s_waitcnt vmcnt(0)" ::: "memory");
        }
        __builtin_amdgcn_s_barrier();
        __builtin_amdgcn_sched_barrier(0);
        const ushort* pa = LA + (t & 3) * 2048;
        const ushort* pb = LB + (t & 3) * 2048;
        s8v a[2], b[2];
#pragma unroll
        for (int m = 0; m < 2; ++m) {
            int row = wr * 32 + m * 16 + rA;
            a[m] = *(const s8v*)&pa[row * 32 + ((kg ^ fsw(row)) << 3)];
        }
#pragma unroll
        for (int n = 0; n < 2; ++n) {
            int row = wc * 32 + n * 16 + rA;
            b[n] = *(const s8v*)&pb[row * 32 + ((kg ^ fsw(row)) << 3)];
        }
#pragma unroll
        for (int m = 0; m < 2; ++m)
#pragma unroll
            for (int n = 0; n < 2; ++n)
                acc[m][n] = __builtin_amdgcn_mfma_f32_16x16x32_bf16(a[m], b[n], acc[m][n], 0, 0, 0);
    }
    const int r4 = (lane >> 4) * 4, cl = lane & 15;
    if (OBF) {
        ushort* O = (ushort*)Oraw;
#pragma unroll
        for (int m = 0; m < 2; ++m)
#pragma unroll
            for (int n = 0; n < 2; ++n) {
                int row = row0 + wr * 32 + m * 16 + r4;
                int col = col0 + wc * 32 + n * 16 + cl;
#pragma unroll
                for (int r = 0; r < 4; ++r)
                    O[(size_t)(row + r) * ldo + col] = f2bf(acc[m][n][r]);
            }
    } else {
        float* O = (float*)Oraw;
#pragma unroll
        for (int m = 0; m < 2; ++m)
#pragma unroll
            for (int n = 0; n < 2; ++n) {
                int row = row0 + wr * 32 + m * 16 + r4;
                int col = col0 + wc * 32 + n * 16 + cl;
#pragma unroll
                for (int r = 0; r < 4; ++r)
                    O[(size_t)(row + r) * ldo + col] = acc[m][n][r] + bias[row + r];
            }
    }
}

// ===== kernel 1: 544 blocks x 512 thr (unchanged, proven).
__global__ __launch_bounds__(512, 2) void kSP(
    const float* __restrict__ x, const float* __restrict__ Wq,
    const float* __restrict__ Wk, const float* __restrict__ Wv,
    const float* __restrict__ Wo,
    ushort* __restrict__ S16, ushort* __restrict__ A16,
    ushort* __restrict__ BT, ushort* __restrict__ xlc) {
    __shared__ __align__(16) ushort lds[32768];
    const int bid = blockIdx.x, tid = threadIdx.x;
    if (bid < 160) {
        int xcd = bid & 7, idx = bid >> 3;
        int b = 2 * xcd + (idx >= 10);
        int tri = (idx >= 10) ? idx - 10 : idx;
        int ti, tj;
        if (tri < 4)      { ti = 0; tj = tri; }
        else if (tri < 7) { ti = 1; tj = tri - 3; }
        else if (tri < 9) { ti = 2; tj = tri - 5; }
        else              { ti = 3; tj = 3; }
        const float* xb = x + (size_t)b * 262144;
        gemmS(xb, lds, ti * 64, tj * 64, S16 + (size_t)b * 65536, ti != tj);
    } else if (bid < 224) {
        int q = bid - 160, h = q >> 4, t2 = q & 15;
        gemmWT<1>(Wq + (size_t)h * 65536, Wk + (size_t)h * 65536, lds,
                  (t2 >> 2) * 64, (t2 & 3) * 64, A16 + (size_t)h * 65536, 256);
    } else if (bid < 288) {
        int q = bid - 224, h = q >> 4, t2 = q & 15;
        gemmWT<0>(Wo + (size_t)h * 256, Wv + (size_t)h * 65536, lds,
                  (t2 >> 2) * 64, (t2 & 3) * 64, BT + (size_t)h * 256, 1024);
    } else {
        ushort (*t)[72] = (ushort(*)[72])lds;
        int r = tid >> 3, c0 = (tid & 7) * 8;
#pragma unroll
        for (int rr = 0; rr < 4; ++rr) {
            int jid = (bid - 288) + 256 * rr;       // 0..1023
            __syncthreads();
            int lt = jid & 15, ct = (jid >> 4) & 3, b2 = jid >> 6;
            size_t so = (size_t)(b2 * 256 + ct * 64 + r) * 1024 + lt * 64 + c0;
            float4 v0 = *(const float4*)(x + so);
            float4 v1 = *(const float4*)(x + so + 4);
            ushort4 u0 = { f2bf(v0.x), f2bf(v0.y), f2bf(v0.z), f2bf(v0.w) };
            ushort4 u1 = { f2bf(v1.x), f2bf(v1.y), f2bf(v1.z), f2bf(v1.w) };
            *(ushort4*)&t[r][c0] = u0;
            *(ushort4*)&t[r][c0 + 4] = u1;
            __syncthreads();
            size_t dof = (size_t)(b2 * 1024 + lt * 64 + r) * 256 + ct * 64 + c0;
            ushort4 w0 = { t[c0][r], t[c0 + 1][r], t[c0 + 2][r], t[c0 + 3][r] };
            ushort4 w1 = { t[c0 + 4][r], t[c0 + 5][r], t[c0 + 6][r], t[c0 + 7][r] };
            *(ushort4*)(xlc + dof) = w0;
            *(ushort4*)(xlc + dof + 4) = w1;
        }
    }
}

// ===== kernel 2: T1_b[:, h*256:] = A_h @ S_b^T — 1024 blocks x 256 thr (64² tiles)
__global__ __launch_bounds__(256, 2) void kT1(
    const ushort* __restrict__ A16, const ushort* __restrict__ S16,
    ushort* __restrict__ T1) {
    __shared__ __align__(16) ushort lds[16384];
    int bid = blockIdx.x, xcd = bid & 7, idx = bid >> 3;   // idx 0..127
    int b = 2 * xcd + (idx >> 6);
    int q = idx & 63;                                       // h,r,c
    int h = q >> 4, r = (q >> 2) & 3, c = q & 3;
    gemm64q<8, 1>(A16 + (size_t)h * 65536, S16 + (size_t)b * 65536, 256, 256, lds,
                  r * 64, c * 64, T1 + (size_t)b * 262144 + h * 256, 1024, nullptr);
}

// ===== kernel 3: GT_b = BT @ T1_b^T (K=1024) — 256 blocks x 512 thr (unchanged)
__global__ __launch_bounds__(512, 2) void kGT(
    const ushort* __restrict__ BT, const ushort* __restrict__ T1,
    ushort* __restrict__ GT) {
    __shared__ __align__(16) ushort lds[32768];
    int j = blockIdx.x, xcd = j & 7, idx = j >> 3;
    int b = 2 * xcd + (idx >> 4), tile = idx & 15;
    gemm64x8(BT, T1 + (size_t)b * 262144, 1024, 1024, lds,
             (tile >> 2) * 64, (tile & 3) * 64, 1024, GT + (size_t)b * 65536, 256);
}

// ===== kernel 4: out_b = GT_b @ xlc_b^T + bias — 1024 blocks x 256 thr (64² tiles)
__global__ __launch_bounds__(256, 2) void kOUT(
    const ushort* __restrict__ GT, const ushort* __restrict__ xlc,
    float* __restrict__ out, const float* __restrict__ bias) {
    __shared__ __align__(16) ushort lds[16384];
    int bid = blockIdx.x, xcd = bid & 7, idx = bid >> 3;   // idx 0..127
    int b = 2 * xcd + (idx >> 6);
    int q = idx & 63;                                       // rt 0..3, ct 0..15
    gemm64q<8, 0>(GT + (size_t)b * 65536, xlc + (size_t)b * 262144, 256, 256, lds,
                  (q >> 4) * 64, (q & 15) * 64, out + (size_t)b * 262144, 1024, bias);
}

extern "C" void kernel_launch(void* const* d_in, const int* in_sizes, int n_in,
                              void* d_out, int out_size, void* d_ws, size_t ws_size,
                              hipStream_t stream) {
    const float* x  = (const float*)d_in[0];
    const float* Wq = (const float*)d_in[1];
    const float* Wk = (const float*)d_in[2];
    const float* Wv = (const float*)d_in[3];
    const float* Wo = (const float*)d_in[4];
    const float* Wb = (const float*)d_in[5];

    char* ws = (char*)d_ws;
    ushort* T1  = (ushort*)(ws + 0);           // [16][256][1024] bf16, 8 MB
    ushort* xlc = (ushort*)(ws + 8388608);     // [16][1024][256] bf16, 8 MB
    ushort* S16 = (ushort*)(ws + 16777216);    // [16][256][256]  bf16, 2 MB
    ushort* GT  = (ushort*)(ws + 20971520);    // [16][256][256]  bf16, 2 MB
    ushort* A16 = (ushort*)(ws + 25165824);    // [4][256][256]   bf16, 512 KB
    ushort* BT  = (ushort*)(ws + 26214400);    // [256][1024]     bf16, 512 KB

    hipLaunchKernelGGL(kSP,  dim3(544), dim3(512), 0, stream,
                       x, Wq, Wk, Wv, Wo, S16, A16, BT, xlc);
    hipLaunchKernelGGL(kT1,  dim3(1024), dim3(256), 0, stream, A16, S16, T1);
    hipLaunchKernelGGL(kGT,  dim3(256), dim3(512), 0, stream, BT, T1, GT);
    hipLaunchKernelGGL(kOUT, dim3(1024), dim3(256), 0, stream, GT, xlc, (float*)d_out, Wb);
}